// Round 14
// baseline (364.657 us; speedup 1.0000x reference)
//
#include <hip/hip_runtime.h>
#include <cstdint>
#include <cstddef>

#define NN 50000
#define EE 800000
#define DD 128
#define NBLK 196    // ceil(NN/256)

// ---------------- ws layout (bytes) ----------------
// deg      [N] int      @ 0        (200000)
// bsum     [NBLK] int   @ 200000   (784)
// boff     [NBLK+1] int @ 200832   (788)
// row_ptr  [N+1] int    @ 400000   (200004)
// rank     [E] int      @ 600064   (3200000)
// dinv     [N] float    @ 3800064  (200000)
// flag     [1] int      @ 4000064  (4)
// H        [N*D] bf16   @ 4000256  (12800000)
// csr      [E] uint2    @ 16800256 (6400000)   -- packed (src, bitcast(dinv[src]))
// WhT      [3][D*D]bf16 @ 23200256 (98304)     -- W hi, TRANSPOSED [n][k], per layer
// WlT      [3][D*D]bf16 @ 23298560 (98304)     -- W lo residual
// total: 23,396,864 bytes

using bf16x8 = __attribute__((ext_vector_type(8))) short;   // 8 bf16 (4 VGPRs)
using f32x4  = __attribute__((ext_vector_type(4))) float;

// fp32 -> bf16 (RNE) and bf16-pair unpack
__device__ __forceinline__ unsigned int f2bf(float f) {
    unsigned int u = __float_as_uint(f);
    u += 0x7fffu + ((u >> 16) & 1u);
    return u >> 16;
}
__device__ __forceinline__ float bf2f(unsigned int hi) { return __uint_as_float(hi << 16); }
__device__ __forceinline__ float bflo(unsigned int u) { return __uint_as_float(u << 16); }
__device__ __forceinline__ float bfhi(unsigned int u) { return __uint_as_float(u & 0xffff0000u); }

// 8 bf16 (one 256b row chunk) * w -> acc[8]; static indexing keeps acc in VGPRs
__device__ __forceinline__ void acc8(float* acc, uint4 q, float w) {
    acc[0] = fmaf(bflo(q.x), w, acc[0]);
    acc[1] = fmaf(bfhi(q.x), w, acc[1]);
    acc[2] = fmaf(bflo(q.y), w, acc[2]);
    acc[3] = fmaf(bfhi(q.y), w, acc[3]);
    acc[4] = fmaf(bflo(q.z), w, acc[4]);
    acc[5] = fmaf(bfhi(q.z), w, acc[5]);
    acc[6] = fmaf(bflo(q.w), w, acc[6]);
    acc[7] = fmaf(bfhi(q.w), w, acc[7]);
}

__device__ __forceinline__ int ld_idx(const int* __restrict__ p, long long i, int mode64) {
    return mode64 ? p[2 * i] : p[(size_t)i];
}

// Detect whether edge_index arrived as int64 (high dwords all zero) or int32.
__global__ void probe_kernel(const int* __restrict__ ei, int* __restrict__ flag) {
    int t = threadIdx.x;
    int v = ei[2 * t + 1];
    unsigned long long b = __ballot(v != 0);
    if (t == 0) *flag = (b == 0ull) ? 1 : 0;
}

// deg count; atomic return value doubles as the edge's within-row rank.
__global__ void count_kernel(const int* __restrict__ ei, const int* __restrict__ flag,
                             int* __restrict__ deg, int* __restrict__ rank) {
    int e = blockIdx.x * 256 + threadIdx.x;
    if (e >= EE) return;
    int m = *flag;
    int d = ld_idx(ei, (long long)EE + e, m);
    rank[e] = atomicAdd(&deg[d], 1);
}

// ---- decoupled scan ----
__global__ __launch_bounds__(256) void partial_kernel(const int* __restrict__ deg,
                                                      int* __restrict__ bsum) {
    int idx = blockIdx.x * 256 + threadIdx.x;
    int v = (idx < NN) ? deg[idx] : 0;
    for (int off = 1; off < 64; off <<= 1) v += __shfl_xor(v, off);
    __shared__ int ws[4];
    if ((threadIdx.x & 63) == 0) ws[threadIdx.x >> 6] = v;
    __syncthreads();
    if (threadIdx.x == 0) bsum[blockIdx.x] = ws[0] + ws[1] + ws[2] + ws[3];
}

__global__ __launch_bounds__(256) void bscan_kernel(const int* __restrict__ bsum,
                                                    int* __restrict__ boff) {
    __shared__ int sh[256];
    int t = threadIdx.x;
    sh[t] = (t < NBLK) ? bsum[t] : 0;
    __syncthreads();
    for (int off = 1; off < 256; off <<= 1) {
        int u = (t >= off) ? sh[t - off] : 0;
        __syncthreads();
        sh[t] += u;
        __syncthreads();
    }
    if (t <= NBLK) boff[t] = (t == 0) ? 0 : sh[t - 1];
}

__global__ __launch_bounds__(256) void scatter_scan_kernel(
        const int* __restrict__ deg, const int* __restrict__ boff,
        int* __restrict__ row_ptr, float* __restrict__ dinv) {
    __shared__ int sh[256];
    int t = threadIdx.x;
    int idx = blockIdx.x * 256 + t;
    int v = (idx < NN) ? deg[idx] : 0;
    sh[t] = v;
    __syncthreads();
    for (int off = 1; off < 256; off <<= 1) {
        int u = (t >= off) ? sh[t - off] : 0;
        __syncthreads();
        sh[t] += u;
        __syncthreads();
    }
    if (idx < NN) {
        row_ptr[idx] = boff[blockIdx.x] + sh[t] - v;
        dinv[idx] = rsqrtf((float)(v + 1));
    }
    if (idx == 0) row_ptr[NN] = boff[NBLK];
}

// No atomic: pos = row_ptr[dst] + rank[e].  One packed 8B scattered store.
__global__ void fill_kernel(const int* __restrict__ ei, const int* __restrict__ flag,
                            const int* __restrict__ row_ptr, const int* __restrict__ rank,
                            const float* __restrict__ dinv, uint2* __restrict__ csr) {
    int e = blockIdx.x * 256 + threadIdx.x;
    if (e >= EE) return;
    int m = *flag;
    int sv = ld_idx(ei, (long long)e, m);
    int dv = ld_idx(ei, (long long)EE + e, m);
    int pos = row_ptr[dv] + rank[e];
    csr[pos] = make_uint2((unsigned)sv, __float_as_uint(dinv[sv]));
}

// All 3 layers' W(fp32 [k][n]) -> WhT/WlT (bf16 hi + residual, [n][k]) in one dispatch.
__global__ __launch_bounds__(256) void convw3_kernel(
        const float* __restrict__ W1, const float* __restrict__ W2,
        const float* __restrict__ W3,
        unsigned short* __restrict__ WhT, unsigned short* __restrict__ WlT) {
    int id = blockIdx.x * 256 + threadIdx.x;   // grid 192 -> 49152 = 3*16384
    int layer = id >> 14;
    int i = id & 16383;
    const float* W = (layer == 0) ? W1 : (layer == 1) ? W2 : W3;
    int k = i >> 7, n = i & 127;
    float w = W[i];
    unsigned int hi = f2bf(w);
    unsigned int lo = f2bf(w - bf2f(hi));
    WhT[layer * 16384 + n * 128 + k] = (unsigned short)hi;
    WlT[layer * 16384 + n * 128 + k] = (unsigned short)lo;
}

// H(bf16) = rmsnorm(X,g) @ W via split-bf16 MFMA: h = xh*wh + xh*wl + xl*wh.
// 512 thr = 8 waves, 64 rows/block; wave w: rows (w&3)*16.., cols (w>>2)*64..
// LDS: xh/xl [64][128] bf16, 16B-chunk XOR-swizzled (chunk ^= row&7).
// MFMA 16x16x32: A row=lane&15, k=(lane>>4)*8+j; D col=lane&15, row=(lane>>4)*4+reg.
#define HSTR 136   // repack row stride in shorts (17 uint4): rr,rr+4 differ by 16 banks
__global__ __launch_bounds__(512) void rmsnorm_mfma_kernel(
        const float* __restrict__ X, const unsigned short* __restrict__ WhT,
        const unsigned short* __restrict__ WlT, const float* __restrict__ g,
        uint4* __restrict__ H) {
    __shared__ uint4 smem[2048];          // [0..1023]=xh, [1024..2047]=xl (32KB)
    int t = threadIdx.x;
    int row0 = blockIdx.x * 64;

    // ---- stage + rmsnorm + hi/lo split: 8 threads/row, 16 floats each
    int r = t >> 3, part = t & 7;
    int row = row0 + r;
    float4 v[4];
    float ss = 0.f;
    if (row < NN) {
        const float4* xr = (const float4*)(X + (size_t)row * DD) + part * 4;
        #pragma unroll
        for (int i = 0; i < 4; i++) {
            v[i] = xr[i];
            ss += v[i].x * v[i].x + v[i].y * v[i].y + v[i].z * v[i].z + v[i].w * v[i].w;
        }
    } else {
        #pragma unroll
        for (int i = 0; i < 4; i++) v[i] = make_float4(0.f, 0.f, 0.f, 0.f);
    }
    ss += __shfl_xor(ss, 1);
    ss += __shfl_xor(ss, 2);
    ss += __shfl_xor(ss, 4);
    float sc = rsqrtf(ss * (1.0f / DD) + 1e-6f);

    const float4* g4 = (const float4*)g + part * 4;
    #pragma unroll
    for (int c = 0; c < 2; c++) {         // chunk = 8 floats -> one uint4 of 8 bf16
        float f[8];
        #pragma unroll
        for (int h = 0; h < 2; h++) {
            float4 gq = g4[2 * c + h];
            float4 xv = v[2 * c + h];
            f[4 * h + 0] = xv.x * sc * gq.x;
            f[4 * h + 1] = xv.y * sc * gq.y;
            f[4 * h + 2] = xv.z * sc * gq.z;
            f[4 * h + 3] = xv.w * sc * gq.w;
        }
        unsigned int hb[8], lb[8];
        #pragma unroll
        for (int j = 0; j < 8; j++) {
            hb[j] = f2bf(f[j]);
            lb[j] = f2bf(f[j] - bf2f(hb[j]));
        }
        uint4 hq, lq;
        hq.x = hb[0] | (hb[1] << 16); hq.y = hb[2] | (hb[3] << 16);
        hq.z = hb[4] | (hb[5] << 16); hq.w = hb[6] | (hb[7] << 16);
        lq.x = lb[0] | (lb[1] << 16); lq.y = lb[2] | (lb[3] << 16);
        lq.z = lb[4] | (lb[5] << 16); lq.w = lb[6] | (lb[7] << 16);
        int ch = part * 2 + c;
        int idx = r * 16 + (ch ^ (r & 7));   // swizzled 16B chunk
        smem[idx] = hq;
        smem[1024 + idx] = lq;
    }
    __syncthreads();

    // ---- A-frags to registers (wave w: rows (w&3)*16..+15)
    int w = t >> 6, lane = t & 63;
    int wr = w & 3, wc = w >> 2;
    int kg = lane >> 4;
    int arow = wr * 16 + (lane & 15);
    bf16x8 ah[4], al[4];
    #pragma unroll
    for (int kk = 0; kk < 4; kk++) {
        int idx = arow * 16 + ((kk * 4 + kg) ^ (arow & 7));
        ah[kk] = *(const bf16x8*)&smem[idx];
        al[kk] = *(const bf16x8*)&smem[1024 + idx];
    }
    __syncthreads();

    // ---- MFMA: 4 N-tiles (cols wc*64 + nt*16) x 4 K-steps x 3 (split)
    const bf16x8* whv = (const bf16x8*)WhT;   // [n][k] in bf16x8 units: n*16 + k/8
    const bf16x8* wlv = (const bf16x8*)WlT;
    f32x4 acc[4];
    #pragma unroll
    for (int nt = 0; nt < 4; nt++) acc[nt] = (f32x4){0.f, 0.f, 0.f, 0.f};
    #pragma unroll
    for (int nt = 0; nt < 4; nt++) {
        int bi = (wc * 64 + nt * 16 + (lane & 15)) * 16 + kg;
        #pragma unroll
        for (int kk = 0; kk < 4; kk++) {
            bf16x8 bh = whv[bi + kk * 4];
            bf16x8 bl = wlv[bi + kk * 4];
            acc[nt] = __builtin_amdgcn_mfma_f32_16x16x32_bf16(ah[kk], bh, acc[nt], 0, 0, 0);
            acc[nt] = __builtin_amdgcn_mfma_f32_16x16x32_bf16(al[kk], bh, acc[nt], 0, 0, 0);
            acc[nt] = __builtin_amdgcn_mfma_f32_16x16x32_bf16(ah[kk], bl, acc[nt], 0, 0, 0);
        }
    }

    // ---- repack D through LDS (reuse smem; padded stride) for coalesced stores
    unsigned short* hsm = (unsigned short*)smem;   // [64][HSTR] bf16
    #pragma unroll
    for (int nt = 0; nt < 4; nt++) {
        #pragma unroll
        for (int q = 0; q < 4; q++) {
            int rr = wr * 16 + (lane >> 4) * 4 + q;          // D row
            int cc = wc * 64 + nt * 16 + (lane & 15);        // D col
            hsm[rr * HSTR + cc] = (unsigned short)f2bf(acc[nt][q]);
        }
    }
    __syncthreads();
    if (row < NN) {
        const uint4* hsm4 = (const uint4*)smem;   // row = 17 uint4
        #pragma unroll
        for (int c = 0; c < 2; c++) {
            int ch = part * 2 + c;
            H[(size_t)row * 16 + ch] = hsm4[r * 17 + ch];
        }
    }
}

// out[n] = relu( sum_{e:dst=n} H[src]*w_e*dinv[n] + H[n]*dinv[n]^2 + b )
// One wave per node; 4 groups x 16 lanes x uint4; 4-deep edge pipeline
// (4 independent 16B row-gathers in flight per group; same FMA order as 2-deep).
__global__ __launch_bounds__(256) void aggregate_kernel(
        const unsigned int* __restrict__ Hm, const float* __restrict__ dinv,
        const int* __restrict__ row_ptr, const uint2* __restrict__ csr,
        const float* __restrict__ b, float* __restrict__ out) {
    __shared__ uint2 sEdge[4][64];
    int wv = threadIdx.x >> 6;
    int lane = threadIdx.x & 63;
    int n = blockIdx.x * 4 + wv;          // grid = N/4 exactly
    int grp = lane >> 4;
    int tc = lane & 15;
    const uint4* H4 = (const uint4*)Hm;   // row = 16 uint4 = 256B
    float dn = dinv[n];
    float acc[8];
    #pragma unroll
    for (int i = 0; i < 8; i++) acc[i] = 0.f;

    if (grp == 0) {                       // self loop + bias, added once
        uint4 q = H4[(size_t)n * 16 + tc];
        const float4* b4 = (const float4*)b;
        float4 ba = b4[2 * tc], bb = b4[2 * tc + 1];
        acc[0] = ba.x; acc[1] = ba.y; acc[2] = ba.z; acc[3] = ba.w;
        acc[4] = bb.x; acc[5] = bb.y; acc[6] = bb.z; acc[7] = bb.w;
        acc8(acc, q, dn * dn);
    }

    int start = row_ptr[n], end = row_ptr[n + 1];
    for (int base = start; base < end; base += 64) {
        int m = min(64, end - base);
        if (lane < m) sEdge[wv][lane] = csr[base + lane];
        int j = grp;
        for (; j + 12 < m; j += 16) {     // 4 independent row-gathers in flight
            uint2 pa = sEdge[wv][j];
            uint2 pb = sEdge[wv][j + 4];
            uint2 pc = sEdge[wv][j + 8];
            uint2 pd = sEdge[wv][j + 12];
            uint4 qa = H4[(size_t)pa.x * 16 + tc];
            uint4 qb = H4[(size_t)pb.x * 16 + tc];
            uint4 qc = H4[(size_t)pc.x * 16 + tc];
            uint4 qd = H4[(size_t)pd.x * 16 + tc];
            float wa = __uint_as_float(pa.y) * dn;
            float wb = __uint_as_float(pb.y) * dn;
            float wc = __uint_as_float(pc.y) * dn;
            float wd = __uint_as_float(pd.y) * dn;
            acc8(acc, qa, wa);
            acc8(acc, qb, wb);
            acc8(acc, qc, wc);
            acc8(acc, qd, wd);
        }
        for (; j < m; j += 4) {           // remainder (<=3 per group)
            uint2 p = sEdge[wv][j];
            uint4 q = H4[(size_t)p.x * 16 + tc];
            acc8(acc, q, __uint_as_float(p.y) * dn);
        }
    }

    #pragma unroll
    for (int i = 0; i < 8; i++) {
        acc[i] += __shfl_xor(acc[i], 16);
        acc[i] += __shfl_xor(acc[i], 32);
    }
    if (grp == 0) {
        float4 o0, o1;
        o0.x = fmaxf(acc[0], 0.f); o0.y = fmaxf(acc[1], 0.f);
        o0.z = fmaxf(acc[2], 0.f); o0.w = fmaxf(acc[3], 0.f);
        o1.x = fmaxf(acc[4], 0.f); o1.y = fmaxf(acc[5], 0.f);
        o1.z = fmaxf(acc[6], 0.f); o1.w = fmaxf(acc[7], 0.f);
        float4* orow = (float4*)(out + (size_t)n * DD + 8 * tc);
        orow[0] = o0;
        orow[1] = o1;
    }
}

extern "C" void kernel_launch(void* const* d_in, const int* in_sizes, int n_in,
                              void* d_out, int out_size, void* d_ws, size_t ws_size,
                              hipStream_t stream) {
    (void)in_sizes; (void)n_in; (void)out_size; (void)ws_size;
    const float* x  = (const float*)d_in[0];
    const int*   ei = (const int*)d_in[1];
    const float* W1 = (const float*)d_in[2];
    const float* b1 = (const float*)d_in[3];
    const float* g1 = (const float*)d_in[4];
    const float* W2 = (const float*)d_in[5];
    const float* b2 = (const float*)d_in[6];
    const float* g2 = (const float*)d_in[7];
    const float* W3 = (const float*)d_in[8];
    const float* b3 = (const float*)d_in[9];
    const float* g3 = (const float*)d_in[10];
    float* out = (float*)d_out;

    char* wsb = (char*)d_ws;
    int*   deg     = (int*)(wsb + 0);
    int*   bsum    = (int*)(wsb + 200000);
    int*   boff    = (int*)(wsb + 200832);
    int*   row_ptr = (int*)(wsb + 400000);
    int*   rank    = (int*)(wsb + 600064);
    float* dinv    = (float*)(wsb + 3800064);
    int*   flag    = (int*)(wsb + 4000064);
    unsigned int* Hb = (unsigned int*)(wsb + 4000256);
    uint2* csr     = (uint2*)(wsb + 16800256);
    unsigned short* WhT = (unsigned short*)(wsb + 23200256);
    unsigned short* WlT = (unsigned short*)(wsb + 23298560);

    hipMemsetAsync(deg, 0, 200000, stream);

    convw3_kernel<<<192, 256, 0, stream>>>(W1, W2, W3, WhT, WlT);
    probe_kernel<<<1, 64, 0, stream>>>(ei, flag);
    count_kernel<<<(EE + 255) / 256, 256, 0, stream>>>(ei, flag, deg, rank);
    partial_kernel<<<NBLK, 256, 0, stream>>>(deg, bsum);
    bscan_kernel<<<1, 256, 0, stream>>>(bsum, boff);
    scatter_scan_kernel<<<NBLK, 256, 0, stream>>>(deg, boff, row_ptr, dinv);
    fill_kernel<<<(EE + 255) / 256, 256, 0, stream>>>(ei, flag, row_ptr, rank, dinv, csr);

    const int gemm_grid = (NN + 63) / 64;   // 782
    const int agg_grid  = NN / 4;           // 12500
    uint4* H4 = (uint4*)Hb;

    rmsnorm_mfma_kernel<<<gemm_grid, 512, 0, stream>>>(x, WhT, WlT, g1, H4);
    aggregate_kernel<<<agg_grid, 256, 0, stream>>>(Hb, dinv, row_ptr, csr, b1, out);
    rmsnorm_mfma_kernel<<<gemm_grid, 512, 0, stream>>>(out, WhT + 16384, WlT + 16384, g2, H4);
    aggregate_kernel<<<agg_grid, 256, 0, stream>>>(Hb, dinv, row_ptr, csr, b2, out);
    rmsnorm_mfma_kernel<<<gemm_grid, 512, 0, stream>>>(out, WhT + 32768, WlT + 32768, g3, H4);
    aggregate_kernel<<<agg_grid, 256, 0, stream>>>(Hb, dinv, row_ptr, csr, b3, out);
}

// Round 16
// 360.545 us; speedup vs baseline: 1.0114x; 1.0114x over previous
//
#include <hip/hip_runtime.h>
#include <cstdint>
#include <cstddef>

#define NN 50000
#define EE 800000
#define DD 128
#define NBLK 196       // ceil(NN/256)
#define FILL_BLKS 1563 // ceil(EE/512)
#define GEMM_BLKS 782  // ceil(NN/64)

// ---------------- ws layout (bytes) ----------------
// deg      [N] int      @ 0        (200000)
// bsum     [NBLK] int   @ 200000   (784)
// boff     [NBLK+1] int @ 200832   (788)
// row_ptr  [N+1] int    @ 400000   (200004)
// rank     [E] int      @ 600064   (3200000)
// dinv     [N] float    @ 3800064  (200000)
// flag     [1] int      @ 4000064  (4)
// H        [N*D] bf16   @ 4000256  (12800000)
// csr      [E] uint2    @ 16800256 (6400000)   -- packed (src, bitcast(dinv[src]))
// WhT      [3][D*D]bf16 @ 23200256 (98304)     -- W hi, TRANSPOSED [n][k], per layer
// WlT      [3][D*D]bf16 @ 23298560 (98304)     -- W lo residual
// total: 23,396,864 bytes

using bf16x8 = __attribute__((ext_vector_type(8))) short;   // 8 bf16 (4 VGPRs)
using f32x4  = __attribute__((ext_vector_type(4))) float;

__device__ __forceinline__ unsigned int f2bf(float f) {
    unsigned int u = __float_as_uint(f);
    u += 0x7fffu + ((u >> 16) & 1u);
    return u >> 16;
}
__device__ __forceinline__ float bf2f(unsigned int hi) { return __uint_as_float(hi << 16); }
__device__ __forceinline__ float bflo(unsigned int u) { return __uint_as_float(u << 16); }
__device__ __forceinline__ float bfhi(unsigned int u) { return __uint_as_float(u & 0xffff0000u); }

__device__ __forceinline__ void acc8(float* acc, uint4 q, float w) {
    acc[0] = fmaf(bflo(q.x), w, acc[0]);
    acc[1] = fmaf(bfhi(q.x), w, acc[1]);
    acc[2] = fmaf(bflo(q.y), w, acc[2]);
    acc[3] = fmaf(bfhi(q.y), w, acc[3]);
    acc[4] = fmaf(bflo(q.z), w, acc[4]);
    acc[5] = fmaf(bfhi(q.z), w, acc[5]);
    acc[6] = fmaf(bflo(q.w), w, acc[6]);
    acc[7] = fmaf(bfhi(q.w), w, acc[7]);
}

__device__ __forceinline__ int ld_idx(const int* __restrict__ p, long long i, int mode64) {
    return mode64 ? p[2 * i] : p[(size_t)i];
}

// Detect whether edge_index arrived as int64 (high dwords all zero) or int32.
__global__ void probe_kernel(const int* __restrict__ ei, int* __restrict__ flag) {
    int t = threadIdx.x;
    int v = ei[2 * t + 1];
    unsigned long long b = __ballot(v != 0);
    if (t == 0) *flag = (b == 0ull) ? 1 : 0;
}

// deg count; atomic return value doubles as the edge's within-row rank.
__global__ void count_kernel(const int* __restrict__ ei, const int* __restrict__ flag,
                             int* __restrict__ deg, int* __restrict__ rank) {
    int e = blockIdx.x * 256 + threadIdx.x;
    if (e >= EE) return;
    int m = *flag;
    int d = ld_idx(ei, (long long)EE + e, m);
    rank[e] = atomicAdd(&deg[d], 1);
}

// ---- decoupled scan ----
__global__ __launch_bounds__(256) void partial_kernel(const int* __restrict__ deg,
                                                      int* __restrict__ bsum) {
    int idx = blockIdx.x * 256 + threadIdx.x;
    int v = (idx < NN) ? deg[idx] : 0;
    for (int off = 1; off < 64; off <<= 1) v += __shfl_xor(v, off);
    __shared__ int ws[4];
    if ((threadIdx.x & 63) == 0) ws[threadIdx.x >> 6] = v;
    __syncthreads();
    if (threadIdx.x == 0) bsum[blockIdx.x] = ws[0] + ws[1] + ws[2] + ws[3];
}

__global__ __launch_bounds__(256) void bscan_kernel(const int* __restrict__ bsum,
                                                    int* __restrict__ boff) {
    __shared__ int sh[256];
    int t = threadIdx.x;
    sh[t] = (t < NBLK) ? bsum[t] : 0;
    __syncthreads();
    for (int off = 1; off < 256; off <<= 1) {
        int u = (t >= off) ? sh[t - off] : 0;
        __syncthreads();
        sh[t] += u;
        __syncthreads();
    }
    if (t <= NBLK) boff[t] = (t == 0) ? 0 : sh[t - 1];
}

__global__ __launch_bounds__(256) void scatter_scan_kernel(
        const int* __restrict__ deg, const int* __restrict__ boff,
        int* __restrict__ row_ptr, float* __restrict__ dinv) {
    __shared__ int sh[256];
    int t = threadIdx.x;
    int idx = blockIdx.x * 256 + t;
    int v = (idx < NN) ? deg[idx] : 0;
    sh[t] = v;
    __syncthreads();
    for (int off = 1; off < 256; off <<= 1) {
        int u = (t >= off) ? sh[t - off] : 0;
        __syncthreads();
        sh[t] += u;
        __syncthreads();
    }
    if (idx < NN) {
        row_ptr[idx] = boff[blockIdx.x] + sh[t] - v;
        dinv[idx] = rsqrtf((float)(v + 1));
    }
    if (idx == 0) row_ptr[NN] = boff[NBLK];
}

// All 3 layers' W(fp32 [k][n]) -> WhT/WlT (bf16 hi + residual, [n][k]) in one dispatch.
__global__ __launch_bounds__(256) void convw3_kernel(
        const float* __restrict__ W1, const float* __restrict__ W2,
        const float* __restrict__ W3,
        unsigned short* __restrict__ WhT, unsigned short* __restrict__ WlT) {
    int id = blockIdx.x * 256 + threadIdx.x;   // grid 192 -> 49152 = 3*16384
    int layer = id >> 14;
    int i = id & 16383;
    const float* W = (layer == 0) ? W1 : (layer == 1) ? W2 : W3;
    int k = i >> 7, n = i & 127;
    float w = W[i];
    unsigned int hi = f2bf(w);
    unsigned int lo = f2bf(w - bf2f(hi));
    WhT[layer * 16384 + n * 128 + k] = (unsigned short)hi;
    WlT[layer * 16384 + n * 128 + k] = (unsigned short)lo;
}

// ---- GEMM body (shared by fused and standalone kernels) ----
// H(bf16) = rmsnorm(X,g) @ W via split-bf16 MFMA: h = xh*wh + xh*wl + xl*wh.
// 512 thr = 8 waves, 64 rows; wave w: rows (w&3)*16.., cols (w>>2)*64..
#define HSTR 136   // repack row stride in shorts (17 uint4)
__device__ __forceinline__ void gemm_body(
        int row0, int t,
        const float* __restrict__ X, const unsigned short* __restrict__ WhT,
        const unsigned short* __restrict__ WlT, const float* __restrict__ g,
        uint4* __restrict__ H) {
    __shared__ uint4 smem[2048];          // [0..1023]=xh, [1024..2047]=xl (32KB)

    int r = t >> 3, part = t & 7;
    int row = row0 + r;
    float4 v[4];
    float ss = 0.f;
    if (row < NN) {
        const float4* xr = (const float4*)(X + (size_t)row * DD) + part * 4;
        #pragma unroll
        for (int i = 0; i < 4; i++) {
            v[i] = xr[i];
            ss += v[i].x * v[i].x + v[i].y * v[i].y + v[i].z * v[i].z + v[i].w * v[i].w;
        }
    } else {
        #pragma unroll
        for (int i = 0; i < 4; i++) v[i] = make_float4(0.f, 0.f, 0.f, 0.f);
    }
    ss += __shfl_xor(ss, 1);
    ss += __shfl_xor(ss, 2);
    ss += __shfl_xor(ss, 4);
    float sc = rsqrtf(ss * (1.0f / DD) + 1e-6f);

    const float4* g4 = (const float4*)g + part * 4;
    #pragma unroll
    for (int c = 0; c < 2; c++) {
        float f[8];
        #pragma unroll
        for (int h = 0; h < 2; h++) {
            float4 gq = g4[2 * c + h];
            float4 xv = v[2 * c + h];
            f[4 * h + 0] = xv.x * sc * gq.x;
            f[4 * h + 1] = xv.y * sc * gq.y;
            f[4 * h + 2] = xv.z * sc * gq.z;
            f[4 * h + 3] = xv.w * sc * gq.w;
        }
        unsigned int hb[8], lb[8];
        #pragma unroll
        for (int j = 0; j < 8; j++) {
            hb[j] = f2bf(f[j]);
            lb[j] = f2bf(f[j] - bf2f(hb[j]));
        }
        uint4 hq, lq;
        hq.x = hb[0] | (hb[1] << 16); hq.y = hb[2] | (hb[3] << 16);
        hq.z = hb[4] | (hb[5] << 16); hq.w = hb[6] | (hb[7] << 16);
        lq.x = lb[0] | (lb[1] << 16); lq.y = lb[2] | (lb[3] << 16);
        lq.z = lb[4] | (lb[5] << 16); lq.w = lb[6] | (lb[7] << 16);
        int ch = part * 2 + c;
        int idx = r * 16 + (ch ^ (r & 7));   // swizzled 16B chunk
        smem[idx] = hq;
        smem[1024 + idx] = lq;
    }
    __syncthreads();

    int w = t >> 6, lane = t & 63;
    int wr = w & 3, wc = w >> 2;
    int kg = lane >> 4;
    int arow = wr * 16 + (lane & 15);
    bf16x8 ah[4], al[4];
    #pragma unroll
    for (int kk = 0; kk < 4; kk++) {
        int idx = arow * 16 + ((kk * 4 + kg) ^ (arow & 7));
        ah[kk] = *(const bf16x8*)&smem[idx];
        al[kk] = *(const bf16x8*)&smem[1024 + idx];
    }
    __syncthreads();

    const bf16x8* whv = (const bf16x8*)WhT;
    const bf16x8* wlv = (const bf16x8*)WlT;
    f32x4 acc[4];
    #pragma unroll
    for (int nt = 0; nt < 4; nt++) acc[nt] = (f32x4){0.f, 0.f, 0.f, 0.f};
    #pragma unroll
    for (int nt = 0; nt < 4; nt++) {
        int bi = (wc * 64 + nt * 16 + (lane & 15)) * 16 + kg;
        #pragma unroll
        for (int kk = 0; kk < 4; kk++) {
            bf16x8 bh = whv[bi + kk * 4];
            bf16x8 bl = wlv[bi + kk * 4];
            acc[nt] = __builtin_amdgcn_mfma_f32_16x16x32_bf16(ah[kk], bh, acc[nt], 0, 0, 0);
            acc[nt] = __builtin_amdgcn_mfma_f32_16x16x32_bf16(al[kk], bh, acc[nt], 0, 0, 0);
            acc[nt] = __builtin_amdgcn_mfma_f32_16x16x32_bf16(ah[kk], bl, acc[nt], 0, 0, 0);
        }
    }

    unsigned short* hsm = (unsigned short*)smem;   // [64][HSTR] bf16
    #pragma unroll
    for (int nt = 0; nt < 4; nt++) {
        #pragma unroll
        for (int q = 0; q < 4; q++) {
            int rr = wr * 16 + (lane >> 4) * 4 + q;
            int cc = wc * 64 + nt * 16 + (lane & 15);
            hsm[rr * HSTR + cc] = (unsigned short)f2bf(acc[nt][q]);
        }
    }
    __syncthreads();
    if (row < NN) {
        const uint4* hsm4 = (const uint4*)smem;
        #pragma unroll
        for (int c = 0; c < 2; c++) {
            int ch = part * 2 + c;
            H[(size_t)row * 16 + ch] = hsm4[r * 17 + ch];
        }
    }
}

__global__ __launch_bounds__(512) void rmsnorm_mfma_kernel(
        const float* __restrict__ X, const unsigned short* __restrict__ WhT,
        const unsigned short* __restrict__ WlT, const float* __restrict__ g,
        uint4* __restrict__ H) {
    gemm_body(blockIdx.x * 64, threadIdx.x, X, WhT, WlT, g, H);
}

// Fused: blocks [0,FILL_BLKS) build the csr (fill); rest run layer-1 GEMM.
// Independent outputs (csr vs H); first joint consumer is aggregate1 (next dispatch).
__global__ __launch_bounds__(512) void fill_gemm1_kernel(
        const int* __restrict__ ei, const int* __restrict__ flag,
        const int* __restrict__ row_ptr, const int* __restrict__ rank,
        const float* __restrict__ dinv, uint2* __restrict__ csr,
        const float* __restrict__ X, const unsigned short* __restrict__ WhT,
        const unsigned short* __restrict__ WlT, const float* __restrict__ g,
        uint4* __restrict__ H) {
    if (blockIdx.x < FILL_BLKS) {
        int e = blockIdx.x * 512 + threadIdx.x;
        if (e >= EE) return;
        int m = *flag;
        int sv = ld_idx(ei, (long long)e, m);
        int dv = ld_idx(ei, (long long)EE + e, m);
        int pos = row_ptr[dv] + rank[e];
        csr[pos] = make_uint2((unsigned)sv, __float_as_uint(dinv[sv]));
    } else {
        gemm_body((blockIdx.x - FILL_BLKS) * 64, threadIdx.x, X, WhT, WlT, g, H);
    }
}

// out[n] = relu( sum_{e:dst=n} H[src]*w_e*dinv[n] + H[n]*dinv[n]^2 + b )
// One wave per node; 4 groups x 16 lanes x uint4; 4-deep edge pipeline.
__global__ __launch_bounds__(256) void aggregate_kernel(
        const unsigned int* __restrict__ Hm, const float* __restrict__ dinv,
        const int* __restrict__ row_ptr, const uint2* __restrict__ csr,
        const float* __restrict__ b, float* __restrict__ out) {
    __shared__ uint2 sEdge[4][64];
    int wv = threadIdx.x >> 6;
    int lane = threadIdx.x & 63;
    int n = blockIdx.x * 4 + wv;          // grid = N/4 exactly
    int grp = lane >> 4;
    int tc = lane & 15;
    const uint4* H4 = (const uint4*)Hm;   // row = 16 uint4 = 256B
    float dn = dinv[n];
    float acc[8];
    #pragma unroll
    for (int i = 0; i < 8; i++) acc[i] = 0.f;

    if (grp == 0) {                       // self loop + bias, added once
        uint4 q = H4[(size_t)n * 16 + tc];
        const float4* b4 = (const float4*)b;
        float4 ba = b4[2 * tc], bb = b4[2 * tc + 1];
        acc[0] = ba.x; acc[1] = ba.y; acc[2] = ba.z; acc[3] = ba.w;
        acc[4] = bb.x; acc[5] = bb.y; acc[6] = bb.z; acc[7] = bb.w;
        acc8(acc, q, dn * dn);
    }

    int start = row_ptr[n], end = row_ptr[n + 1];
    for (int base = start; base < end; base += 64) {
        int m = min(64, end - base);
        if (lane < m) sEdge[wv][lane] = csr[base + lane];
        int j = grp;
        for (; j + 12 < m; j += 16) {     // 4 independent row-gathers in flight
            uint2 pa = sEdge[wv][j];
            uint2 pb = sEdge[wv][j + 4];
            uint2 pc = sEdge[wv][j + 8];
            uint2 pd = sEdge[wv][j + 12];
            uint4 qa = H4[(size_t)pa.x * 16 + tc];
            uint4 qb = H4[(size_t)pb.x * 16 + tc];
            uint4 qc = H4[(size_t)pc.x * 16 + tc];
            uint4 qd = H4[(size_t)pd.x * 16 + tc];
            float wa = __uint_as_float(pa.y) * dn;
            float wb = __uint_as_float(pb.y) * dn;
            float wc = __uint_as_float(pc.y) * dn;
            float wd = __uint_as_float(pd.y) * dn;
            acc8(acc, qa, wa);
            acc8(acc, qb, wb);
            acc8(acc, qc, wc);
            acc8(acc, qd, wd);
        }
        for (; j < m; j += 4) {
            uint2 p = sEdge[wv][j];
            uint4 q = H4[(size_t)p.x * 16 + tc];
            acc8(acc, q, __uint_as_float(p.y) * dn);
        }
    }

    #pragma unroll
    for (int i = 0; i < 8; i++) {
        acc[i] += __shfl_xor(acc[i], 16);
        acc[i] += __shfl_xor(acc[i], 32);
    }
    if (grp == 0) {
        float4 o0, o1;
        o0.x = fmaxf(acc[0], 0.f); o0.y = fmaxf(acc[1], 0.f);
        o0.z = fmaxf(acc[2], 0.f); o0.w = fmaxf(acc[3], 0.f);
        o1.x = fmaxf(acc[4], 0.f); o1.y = fmaxf(acc[5], 0.f);
        o1.z = fmaxf(acc[6], 0.f); o1.w = fmaxf(acc[7], 0.f);
        float4* orow = (float4*)(out + (size_t)n * DD + 8 * tc);
        orow[0] = o0;
        orow[1] = o1;
    }
}

extern "C" void kernel_launch(void* const* d_in, const int* in_sizes, int n_in,
                              void* d_out, int out_size, void* d_ws, size_t ws_size,
                              hipStream_t stream) {
    (void)in_sizes; (void)n_in; (void)out_size; (void)ws_size;
    const float* x  = (const float*)d_in[0];
    const int*   ei = (const int*)d_in[1];
    const float* W1 = (const float*)d_in[2];
    const float* b1 = (const float*)d_in[3];
    const float* g1 = (const float*)d_in[4];
    const float* W2 = (const float*)d_in[5];
    const float* b2 = (const float*)d_in[6];
    const float* g2 = (const float*)d_in[7];
    const float* W3 = (const float*)d_in[8];
    const float* b3 = (const float*)d_in[9];
    const float* g3 = (const float*)d_in[10];
    float* out = (float*)d_out;

    char* wsb = (char*)d_ws;
    int*   deg     = (int*)(wsb + 0);
    int*   bsum    = (int*)(wsb + 200000);
    int*   boff    = (int*)(wsb + 200832);
    int*   row_ptr = (int*)(wsb + 400000);
    int*   rank    = (int*)(wsb + 600064);
    float* dinv    = (float*)(wsb + 3800064);
    int*   flag    = (int*)(wsb + 4000064);
    unsigned int* Hb = (unsigned int*)(wsb + 4000256);
    uint2* csr     = (uint2*)(wsb + 16800256);
    unsigned short* WhT = (unsigned short*)(wsb + 23200256);
    unsigned short* WlT = (unsigned short*)(wsb + 23298560);

    hipMemsetAsync(deg, 0, 200000, stream);

    convw3_kernel<<<192, 256, 0, stream>>>(W1, W2, W3, WhT, WlT);
    probe_kernel<<<1, 64, 0, stream>>>(ei, flag);
    count_kernel<<<(EE + 255) / 256, 256, 0, stream>>>(ei, flag, deg, rank);
    partial_kernel<<<NBLK, 256, 0, stream>>>(deg, bsum);
    bscan_kernel<<<1, 256, 0, stream>>>(bsum, boff);
    scatter_scan_kernel<<<NBLK, 256, 0, stream>>>(deg, boff, row_ptr, dinv);

    const int agg_grid = NN / 4;   // 12500
    uint4* H4 = (uint4*)Hb;

    // fill overlapped with layer-1 GEMM (independent; both consumed by aggregate1)
    fill_gemm1_kernel<<<FILL_BLKS + GEMM_BLKS, 512, 0, stream>>>(
        ei, flag, row_ptr, rank, dinv, csr, x, WhT, WlT, g1, H4);
    aggregate_kernel<<<agg_grid, 256, 0, stream>>>(Hb, dinv, row_ptr, csr, b1, out);
    rmsnorm_mfma_kernel<<<GEMM_BLKS, 512, 0, stream>>>(out, WhT + 16384, WlT + 16384, g2, H4);
    aggregate_kernel<<<agg_grid, 256, 0, stream>>>(Hb, dinv, row_ptr, csr, b2, out);
    rmsnorm_mfma_kernel<<<GEMM_BLKS, 512, 0, stream>>>(out, WhT + 32768, WlT + 32768, g3, H4);
    aggregate_kernel<<<agg_grid, 256, 0, stream>>>(Hb, dinv, row_ptr, csr, b3, out);
}